// Round 5
// baseline (349.552 us; speedup 1.0000x reference)
//
#include <hip/hip_runtime.h>

#define LAMBDA_COORD 5.0f
#define LAMBDA_NOOBJ 0.5f
#define DD 30
#define BLOCK 64               // one wave per block
#define CPC 16                 // cells per chunk
#define ITERS 4                // chunks per block -> grid 12544
#define F4C (CPC * DD / 4)     // 120 float4 per input per chunk

__device__ __forceinline__ float iou_t(float tx, float ty, float tw, float th,
                                       float px, float py, float pw, float ph) {
    float xl = fmaxf(tx - tw * 0.5f, px - pw * 0.5f);
    float yt = fmaxf(ty - th * 0.5f, py - ph * 0.5f);
    float xr = fminf(tx + tw * 0.5f, px + pw * 0.5f);
    float yb = fminf(ty + th * 0.5f, py + ph * 0.5f);
    bool valid = (xr >= xl) && (yb >= yt);
    float inter = (xr - xl) * (yb - yt);
    float uni = tw * th + pw * ph - inter;
    float safe = (uni == 0.0f) ? 1.0f : uni;
    return valid ? (inter / safe) : 0.0f;
}

__global__ __launch_bounds__(BLOCK, 6) void yolo_loss_kernel(
    const float* __restrict__ pred, const float* __restrict__ targ,
    float* __restrict__ out) {
    // 2 * 480 floats = 3840 B LDS -> thread-cap-limited 32 blocks/CU
    __shared__ __align__(16) float sp[CPC * DD];
    __shared__ __align__(16) float st[CPC * DD];

    const int tid = threadIdx.x;
    const float4* gp0 = (const float4*)pred + (size_t)blockIdx.x * (ITERS * F4C);
    const float4* gt0 = (const float4*)targ + (size_t)blockIdx.x * (ITERS * F4C);
    float4* lp = (float4*)sp;
    float4* lt = (float4*)st;

    const bool act1 = tid < (F4C - 64);   // 120 = 64 + 56

    // ---- prologue: coalesced float4 prefetch of chunk 0 into registers ----
    float4 RP0, RP1, RT0, RT1;
    RP0 = gp0[tid]; RT0 = gt0[tid];
    if (act1) { RP1 = gp0[64 + tid]; RT1 = gt0[64 + tid]; }

    float acc = 0.0f;

#pragma unroll
    for (int it = 0; it < ITERS; ++it) {
        // phase 1: regs -> LDS (vmcnt wait for chunk `it` lands here,
        // one full compute phase after issue in steady state)
        lp[tid] = RP0; lt[tid] = RT0;
        if (act1) { lp[64 + tid] = RP1; lt[64 + tid] = RT1; }

        // phase 2: issue coalesced loads for chunk it+1; they fly during compute
        if (it + 1 < ITERS) {
            const float4* gp = gp0 + (size_t)(it + 1) * F4C;
            const float4* gt = gt0 + (size_t)(it + 1) * F4C;
            RP0 = gp[tid]; RT0 = gt[tid];
            if (act1) { RP1 = gp[64 + tid]; RT1 = gt[64 + tid]; }
        }

        // phase 3: lanes 0..15 each compute one cell from LDS
        // (single wave: in-order LDS pipe + lgkmcnt gives write->read ordering)
        float v = 0.0f;
        if (tid < CPC) {
            const float* p = &sp[tid * DD];
            const float* t = &st[tid * DD];

            float t4 = t[4];
            float obj = (t4 > 0.0f) ? 1.0f : 0.0f;
            float noobj = (t4 == 0.0f) ? 1.0f : 0.0f;

            float cls = 0.0f;
#pragma unroll
            for (int k = 10; k < 30; ++k) {
                float d = t[k] - p[k];
                cls += d * d;
            }
            cls *= obj;

            float d4 = t4 - p[4];
            float conf_noobj = noobj * d4 * d4;

            float tx = t[0], ty = t[1], tw = t[2], th = t[3];
            float iou1 = iou_t(tx, ty, tw, th, p[0], p[1], p[2], p[3]);
            float iou2 = iou_t(tx, ty, tw, th, p[5], p[6], p[7], p[8]);
            float resp1 = (iou1 > iou2) ? 1.0f : 0.0f;
            float m1 = obj * resp1;
            float m2 = obj * (1.0f - resp1);

            float e1 = iou1 - p[4];
            float e2 = iou2 - p[9];
            float conf_obj = m1 * e1 * e1 + m2 * e2 * e2;

            float dx1 = tx - p[0], dy1 = ty - p[1];
            float dx2 = tx - p[5], dy2 = ty - p[6];
            float xy = m1 * (dx1 * dx1 + dy1 * dy1) + m2 * (dx2 * dx2 + dy2 * dy2);

            float dw1 = tw - p[2], dh1 = th - p[3];
            float dw2 = tw - p[7], dh2 = th - p[8];
            float wh = m1 * (dw1 * dw1 + dh1 * dh1) + m2 * (dw2 * dw2 + dh2 * dh2);

            v = LAMBDA_COORD * (xy + wh) + conf_obj + LAMBDA_NOOBJ * conf_noobj + cls;
        }
        acc += v;
    }

    // ---- 64-lane wave reduction (lanes >= 16 hold 0) ----
#pragma unroll
    for (int off = 32; off > 0; off >>= 1) acc += __shfl_down(acc, off);
    if (tid == 0) atomicAdd(out, acc * (1.0f / 16384.0f));
}

extern "C" void kernel_launch(void* const* d_in, const int* in_sizes, int n_in,
                              void* d_out, int out_size, void* d_ws, size_t ws_size,
                              hipStream_t stream) {
    const float* pred = (const float*)d_in[0];  // y
    const float* targ = (const float*)d_in[1];  // gt
    float* out = (float*)d_out;

    hipMemsetAsync(out, 0, sizeof(float), stream);

    const int cells = in_sizes[0] / DD;          // 802816
    const int grid = cells / (CPC * ITERS);      // 12544 (exact)
    yolo_loss_kernel<<<grid, BLOCK, 0, stream>>>(pred, targ, out);
}

// Round 6
// 209.935 us; speedup vs baseline: 1.6651x; 1.6651x over previous
//
#include <hip/hip_runtime.h>

#define LAMBDA_COORD 5.0f
#define LAMBDA_NOOBJ 0.5f
#define DD 30
#define BLOCK 256

// compile-time element extraction from a float4[15] register array (k must be
// a compile-time constant: fully resolved by constant folding, no scratch)
#define EL(A, k) ((((k) & 3) == 0) ? A[(k) >> 2].x : \
                  (((k) & 3) == 1) ? A[(k) >> 2].y : \
                  (((k) & 3) == 2) ? A[(k) >> 2].z : A[(k) >> 2].w)

__device__ __forceinline__ float iou_t(float tx, float ty, float tw, float th,
                                       float px, float py, float pw, float ph) {
    float xl = fmaxf(tx - tw * 0.5f, px - pw * 0.5f);
    float yt = fmaxf(ty - th * 0.5f, py - ph * 0.5f);
    float xr = fminf(tx + tw * 0.5f, px + pw * 0.5f);
    float yb = fminf(ty + th * 0.5f, py + ph * 0.5f);
    bool valid = (xr >= xl) && (yb >= yt);
    float inter = (xr - xl) * (yb - yt);
    float uni = tw * th + pw * ph - inter;
    float safe = (uni == 0.0f) ? 1.0f : uni;
    return valid ? (inter / safe) : 0.0f;
}

// loss of one cell whose 30 channels start at flat index B within the
// thread's 60-float register window (B = 0 or 30; compile-time)
template <int B>
__device__ __forceinline__ float cell_loss(const float4 (&P)[15], const float4 (&T)[15]) {
    float t4 = EL(T, B + 4);
    float obj = (t4 > 0.0f) ? 1.0f : 0.0f;
    float noobj = (t4 == 0.0f) ? 1.0f : 0.0f;

    float cls = 0.0f;
#pragma unroll
    for (int k = 10; k < 30; ++k) {
        float d = EL(T, B + k) - EL(P, B + k);
        cls += d * d;
    }
    cls *= obj;

    float d4 = t4 - EL(P, B + 4);
    float conf_noobj = noobj * d4 * d4;

    float tx = EL(T, B + 0), ty = EL(T, B + 1), tw = EL(T, B + 2), th = EL(T, B + 3);
    float p0 = EL(P, B + 0), p1 = EL(P, B + 1), p2 = EL(P, B + 2), p3 = EL(P, B + 3);
    float p4 = EL(P, B + 4), p5 = EL(P, B + 5), p6 = EL(P, B + 6), p7 = EL(P, B + 7);
    float p8 = EL(P, B + 8), p9 = EL(P, B + 9);

    float iou1 = iou_t(tx, ty, tw, th, p0, p1, p2, p3);
    float iou2 = iou_t(tx, ty, tw, th, p5, p6, p7, p8);
    float resp1 = (iou1 > iou2) ? 1.0f : 0.0f;
    float m1 = obj * resp1;
    float m2 = obj * (1.0f - resp1);

    float e1 = iou1 - p4;
    float e2 = iou2 - p9;
    float conf_obj = m1 * e1 * e1 + m2 * e2 * e2;

    float dx1 = tx - p0, dy1 = ty - p1;
    float dx2 = tx - p5, dy2 = ty - p6;
    float xy = m1 * (dx1 * dx1 + dy1 * dy1) + m2 * (dx2 * dx2 + dy2 * dy2);

    float dw1 = tw - p2, dh1 = th - p3;
    float dw2 = tw - p7, dh2 = th - p8;
    float wh = m1 * (dw1 * dw1 + dh1 * dh1) + m2 * (dw2 * dw2 + dh2 * dh2);

    return LAMBDA_COORD * (xy + wh) + conf_obj + LAMBDA_NOOBJ * conf_noobj + cls;
}

__global__ __launch_bounds__(BLOCK, 2) void yolo_loss_kernel(
    const float* __restrict__ pred, const float* __restrict__ targ,
    float* __restrict__ out) {
    __shared__ float wpart[BLOCK / 64];

    const int tid = threadIdx.x;
    const size_t pair = (size_t)blockIdx.x * BLOCK + tid;  // cell-pair index

    // cell-pair = 2 cells = 60 floats = 240 B = 15 aligned float4
    const float4* gp = (const float4*)pred + pair * 15;
    const float4* gt = (const float4*)targ + pair * 15;

    float4 P[15], T[15];
#pragma unroll
    for (int j = 0; j < 15; ++j) P[j] = gp[j];
#pragma unroll
    for (int j = 0; j < 15; ++j) T[j] = gt[j];

    float loss = cell_loss<0>(P, T) + cell_loss<30>(P, T);

    // ---- 64-lane wave reduction, then block reduction, one atomic/block ----
#pragma unroll
    for (int off = 32; off > 0; off >>= 1) loss += __shfl_down(loss, off);
    if ((tid & 63) == 0) wpart[tid >> 6] = loss;
    __syncthreads();
    if (tid == 0) {
        float s = wpart[0] + wpart[1] + wpart[2] + wpart[3];
        atomicAdd(out, s * (1.0f / 16384.0f));
    }
}

extern "C" void kernel_launch(void* const* d_in, const int* in_sizes, int n_in,
                              void* d_out, int out_size, void* d_ws, size_t ws_size,
                              hipStream_t stream) {
    const float* pred = (const float*)d_in[0];  // y
    const float* targ = (const float*)d_in[1];  // gt
    float* out = (float*)d_out;

    hipMemsetAsync(out, 0, sizeof(float), stream);

    const int cells = in_sizes[0] / DD;     // 802816
    const int pairs = cells / 2;            // 401408
    const int grid = pairs / BLOCK;         // 1568 (exact)
    yolo_loss_kernel<<<grid, BLOCK, 0, stream>>>(pred, targ, out);
}